// Round 17
// baseline (596.476 us; speedup 1.0000x reference)
//
#include <hip/hip_runtime.h>
#include <cmath>

#define RTOT 8192        // B*C rows
#define NDWT 722         // SEQ_LEN/2+2
#define KP1  736         // NDWT padded to 32
#define LSEQ 1440
#define NHEAD 362        // PRED_LEN/2+2
#define NFREQ 362

typedef __bf16 bf16x8 __attribute__((ext_vector_type(8)));
typedef float f32x4 __attribute__((ext_vector_type(4)));
typedef float f32x2 __attribute__((ext_vector_type(2)));

__device__ __forceinline__ unsigned short f2bf(float f) {
    unsigned u = __float_as_uint(f);
    u += 0x7fffu + ((u >> 16) & 1u);
    return (unsigned short)(u >> 16);
}
__device__ __forceinline__ float bf2f(unsigned short u) {
    return __uint_as_float(((unsigned)u) << 16);
}

// complex MAC: s += a*w  (2x v_pk_fma_f32 via op_sel)
__device__ __forceinline__ void cmac(f32x2& s, f32x2 a, f32x2 w) {
    asm("v_pk_fma_f32 %0, %1, %2, %0 op_sel:[0,0,0] op_sel_hi:[0,1,1]\n\t"
        "v_pk_fma_f32 %0, %1, %2, %0 op_sel:[1,1,0] op_sel_hi:[1,0,1] neg_lo:[0,1,0]"
        : "+v"(s) : "v"(a), "v"(w));
}
// paired-conjugate MAC: s += a*w + b*conj(w), u = a+b, v = a-b
__device__ __forceinline__ void cmac2(f32x2& s, f32x2 u, f32x2 v, f32x2 w) {
    asm("v_pk_fma_f32 %0, %1, %3, %0 op_sel:[0,0,0] op_sel_hi:[1,0,1]\n\t"
        "v_pk_fma_f32 %0, %2, %3, %0 op_sel:[1,1,0] op_sel_hi:[0,1,1] neg_lo:[0,1,0]"
        : "+v"(s) : "v"(u), "v"(v), "v"(w));
}
// complex mul: r = a*b (v_pk_mul + v_pk_fma)
__device__ __forceinline__ f32x2 cmul(f32x2 a, f32x2 b) {
    f32x2 r;
    asm("v_pk_mul_f32 %0, %1, %2 op_sel:[0,0] op_sel_hi:[0,1]\n\t"
        "v_pk_fma_f32 %0, %1, %2, %0 op_sel:[1,1,0] op_sel_hi:[1,0,1] neg_lo:[0,1,0]"
        : "=&v"(r) : "v"(a), "v"(b));
    return r;
}

__constant__ float c_lo[6] = {0.035226291882100656f, -0.08544127388224149f, -0.13501102001039084f,
                              0.4598775021193313f, 0.8068915093133388f, 0.3326705529509569f};
__constant__ float c_hi[6] = {-0.3326705529509569f, 0.8068915093133388f, -0.4598775021193313f,
                              -0.13501102001039084f, 0.08544127388224149f, 0.035226291882100656f};

// ---------------- batched weight fp32 -> bf16 convert; blockIdx.y==17 computes twiddle table ----------------
struct CvtDesc { const float* src; unsigned short* dst; int N, K, Np, Kp; };
struct CvtArgs { CvtDesc d[17]; float2* wtab; };
__global__ __launch_bounds__(256) void cvt_all_kernel(CvtArgs a) {
    if (blockIdx.y == 17) {
        int m = blockIdx.x * 256 + threadIdx.x;
        if (m < NDWT) {
            double ang = -2.0 * 3.141592653589793238462643383279502884 * (double)m / (double)NDWT;
            a.wtab[m] = make_float2((float)cos(ang), (float)sin(ang));
        }
        return;
    }
    CvtDesc d = a.d[blockIdx.y];
    int idx = blockIdx.x * 256 + threadIdx.x;
    int tot = d.Np * d.Kp;
    if (idx >= tot) return;
    int r = idx / d.Kp, c = idx - r * d.Kp;
    float v = (r < d.N && c < d.K) ? d.src[(size_t)r * d.K + c] : 0.f;
    d.dst[idx] = f2bf(v);
}

// ---------------- DWT via LDS transpose: x (64,1440,128) -> ac0, dc0 (8192,722) ----------------
__global__ __launch_bounds__(256) void dwt_kernel(const float* __restrict__ x,
                                                  float* __restrict__ ac0,
                                                  float* __restrict__ dc0) {
    __shared__ float xs[68][129];
    const int b = blockIdx.x;
    const int t0 = blockIdx.y * 32;
    const int tid = threadIdx.x;
    const int lbase = 2 * t0 - 4;
    for (int i = tid; i < 68 * 32; i += 256) {
        int ri = i >> 5;
        int c4 = (i & 31) * 4;
        int l = lbase + ri;
        float4 v = make_float4(0.f, 0.f, 0.f, 0.f);
        if (l >= 0 && l < LSEQ)
            v = *reinterpret_cast<const float4*>(&x[((size_t)b * LSEQ + l) * 128 + c4]);
        xs[ri][c4] = v.x; xs[ri][c4 + 1] = v.y; xs[ri][c4 + 2] = v.z; xs[ri][c4 + 3] = v.w;
    }
    __syncthreads();
    const int tt = tid & 31;
    const int t = t0 + tt;
    const int cw = tid >> 5;
    if (t < NDWT) {
        #pragma unroll 4
        for (int co = 0; co < 16; co++) {
            int c = co * 8 + cw;
            float slo = 0.f, shi = 0.f;
            #pragma unroll
            for (int j = 0; j < 6; j++) {
                float v = xs[2 * tt + 5 - j][c];
                slo += v * c_lo[j];
                shi += v * c_hi[j];
            }
            size_t o = ((size_t)b * 128 + c) * NDWT + t;
            ac0[o] = slo;
            dc0[o] = shi;
        }
    }
}

__device__ __forceinline__ float blockSum256(float v, float* red) {
    #pragma unroll
    for (int o = 32; o > 0; o >>= 1) v += __shfl_down(v, o, 64);
    int lane = threadIdx.x & 63, wid = threadIdx.x >> 6;
    __syncthreads();
    if (lane == 0) red[wid] = v;
    __syncthreads();
    return red[0] + red[1] + red[2] + red[3];
}

// sliding-window 25-tap mean over rowv[0..721] -> pool[0..697]; 3 outputs/thread
template <bool ABS>
__device__ __forceinline__ void pool25(const float* rowv, float* pool, int tid) {
    int i0 = tid * 3;
    if (i0 < 698) {
        float s25 = 0.f;
        #pragma unroll
        for (int j = 0; j < 25; j++) { float v = rowv[i0 + j]; s25 += ABS ? fabsf(v) : v; }
        pool[i0] = s25 * (1.f / 25.f);
        #pragma unroll
        for (int qq = 1; qq < 3; qq++) {
            int i = i0 + qq;
            if (i < 698) {
                float vin = rowv[i + 24], vout = rowv[i - 1];
                s25 += (ABS ? fabsf(vin) : vin) - (ABS ? fabsf(vout) : vout);
                pool[i] = s25 * (1.f / 25.f);
            }
        }
    }
}

// ---------------- FFT-722, IN-PLACE, group-restructured + conjugate-pair DFT-19 ----------------
__device__ void fft722_dev(f32x2* X, f32x2* T, const f32x2* Wt, const f32x2* W19) {
    const int tid = threadIdx.x;
    if (tid < 190) {
        const int c = tid / 38;
        const int g = tid - c * 38;
        const int p = (g >= 19) ? 1 : 0;
        const int rr = g - 19 * p;
        const int t0 = c * 4;
        const int nt = (c == 4) ? 3 : 4;
        const f32x2* xp = X + 2 * rr + p;
        f32x2 st[4], w[4], s[4];
        f32x2 a0 = xp[0];
        #pragma unroll
        for (int i = 0; i < 4; i++) {
            int ti = t0 + i; if (ti > 18) ti = 0;
            st[i] = W19[ti];
            w[i] = st[i];
            s[i] = a0;
        }
        #pragma unroll
        for (int m = 1; m <= 9; m++) {
            f32x2 a = xp[38 * m];
            f32x2 b = xp[38 * (19 - m)];
            f32x2 u = a + b, v = a - b;
            #pragma unroll
            for (int i = 0; i < 4; i++) {
                cmac2(s[i], u, v, w[i]);
                if (m < 9) w[i] = cmul(w[i], st[i]);
            }
        }
        int m0 = rr * t0;
        f32x2* Tp = T + p * 361 + rr * 19 + t0;
        #pragma unroll
        for (int i = 0; i < 4; i++) {
            if (i < nt) Tp[i] = cmul(s[i], Wt[2 * m0]);
            m0 += rr;
        }
    }
    __syncthreads();
    if (tid < 190) {
        const int c = tid / 38;
        const int g = tid - c * 38;
        const int p = (g >= 19) ? 1 : 0;
        const int t = g - 19 * p;
        const int jj0 = c * 4;
        const int nj = (c == 4) ? 3 : 4;
        const f32x2* Ap = T + p * 361 + t;
        f32x2 st[4], w[4], s[4];
        f32x2 a0 = Ap[0];
        #pragma unroll
        for (int i = 0; i < 4; i++) {
            int jj = jj0 + i; if (jj > 18) jj = 0;
            st[i] = W19[jj];
            w[i] = st[i];
            s[i] = a0;
        }
        #pragma unroll
        for (int m = 1; m <= 9; m++) {
            f32x2 a = Ap[19 * m];
            f32x2 b = Ap[19 * (19 - m)];
            f32x2 u = a + b, v = a - b;
            #pragma unroll
            for (int i = 0; i < 4; i++) {
                cmac2(s[i], u, v, w[i]);
                if (m < 9) w[i] = cmul(w[i], st[i]);
            }
        }
        f32x2* Xp = X + p * 361;
        #pragma unroll
        for (int i = 0; i < 4; i++) {
            int jj = jj0 + i;
            if (i < nj) Xp[t + 19 * jj] = s[i];
        }
    }
    __syncthreads();
    for (int k = tid; k < 361; k += 256) {
        f32x2 e = X[k], o = X[361 + k], w = Wt[k];
        f32x2 tt = {0.f, 0.f};
        cmac(tt, o, w);
        X[k] = e + tt;
        X[361 + k] = e - tt;
    }
    __syncthreads();
}

// ---------------- FFT-361 (19 x 19), X[0..360] in place, scratch T[0..360] ----------------
__device__ void fft361_dev(f32x2* X, f32x2* T, const f32x2* Wt, const f32x2* W19) {
    const int tid = threadIdx.x;
    if (tid < 95) {
        const int a = tid / 5;
        const int ch = tid % 5;
        const int t0 = ch * 4;
        const int nt = (ch == 4) ? 3 : 4;
        const f32x2* xp = X + a;
        f32x2 st[4], w[4], s[4];
        f32x2 a0 = xp[0];
        #pragma unroll
        for (int i = 0; i < 4; i++) {
            int ti = t0 + i; if (ti > 18) ti = 0;
            st[i] = W19[ti];
            w[i] = st[i];
            s[i] = a0;
        }
        #pragma unroll
        for (int m = 1; m <= 9; m++) {
            f32x2 aa = xp[19 * m];
            f32x2 bb = xp[19 * (19 - m)];
            f32x2 u = aa + bb, v = aa - bb;
            #pragma unroll
            for (int i = 0; i < 4; i++) {
                cmac2(s[i], u, v, w[i]);
                if (m < 9) w[i] = cmul(w[i], st[i]);
            }
        }
        int m0 = a * t0;
        f32x2* Tp = T + a * 19 + t0;
        #pragma unroll
        for (int i = 0; i < 4; i++) {
            if (i < nt) Tp[i] = cmul(s[i], Wt[2 * m0]);
            m0 += a;
        }
    }
    __syncthreads();
    if (tid < 95) {
        const int t = tid / 5;
        const int ch = tid % 5;
        const int c0 = ch * 4;
        const int nc = (ch == 4) ? 3 : 4;
        const f32x2* Ap = T + t;
        f32x2 st[4], w[4], s[4];
        f32x2 a0 = Ap[0];
        #pragma unroll
        for (int i = 0; i < 4; i++) {
            int cc = c0 + i; if (cc > 18) cc = 0;
            st[i] = W19[cc];
            w[i] = st[i];
            s[i] = a0;
        }
        #pragma unroll
        for (int m = 1; m <= 9; m++) {
            f32x2 aa = Ap[19 * m];
            f32x2 bb = Ap[19 * (19 - m)];
            f32x2 u = aa + bb, v = aa - bb;
            #pragma unroll
            for (int i = 0; i < 4; i++) {
                cmac2(s[i], u, v, w[i]);
                if (m < 9) w[i] = cmul(w[i], st[i]);
            }
        }
        #pragma unroll
        for (int i = 0; i < 4; i++) {
            int cc = c0 + i;
            if (i < nc) X[t + 19 * cc] = s[i];
        }
    }
    __syncthreads();
}

// ---------------- FUSED per-row: stats + packed FFT + top-k mix + real-iFFT(361) + xr-IWT ----------------
__global__ __launch_bounds__(256) void stats_fft_kernel(
    const float* __restrict__ ac0in,
    const float* __restrict__ dc0in,
    unsigned short* __restrict__ cent,  // [4][RTOT][KP1]
    float* __restrict__ stat,           // [4][RTOT]
    unsigned short* __restrict__ xrbf,  // [RTOT*16][96]
    const f32x2* __restrict__ Wtab) {
    __shared__ f32x2 Wt[NDWT];
    __shared__ f32x2 W19s[19];
    __shared__ f32x2 B1[NDWT];
    __shared__ float acpL[NDWT];
    __shared__ __align__(16) char arena[8704];
    __shared__ unsigned hist[256];
    __shared__ unsigned suf[256];
    __shared__ unsigned sh_digit, sh_rem;
    f32x2* B2   = (f32x2*)arena;
    float* smag = (float*)(arena + 5776);
    float* row  = (float*)arena;
    float* xc   = (float*)(arena + 2888);
    float* pool = (float*)(arena + 5776);
    float* red  = (float*)(arena + 8568);
    const int r = blockIdx.x, tid = threadIdx.x;
    const int lane = tid & 63;
    const size_t base = (size_t)r * NDWT;
    const size_t baseP = (size_t)r * KP1;
    const size_t CS = (size_t)RTOT * KP1;

    for (int i = tid; i < NDWT; i += 256) Wt[i] = Wtab[i];
    if (tid < 19) W19s[tid] = Wtab[38 * tid];

    // ================= AC phase =================
    for (int i = tid; i < NDWT; i += 256) row[i] = ac0in[base + i];
    __syncthreads();
    float s = 0.f;
    for (int i = tid; i < NDWT; i += 256) s += row[i];
    float mean = blockSum256(s, red) * (1.f / 722.f);
    s = 0.f;
    for (int i = tid; i < NDWT; i += 256) s += row[i] - mean;
    float m2 = blockSum256(s, red) * (1.f / 722.f);
    s = 0.f;
    for (int i = tid; i < NDWT; i += 256) { float d = row[i] - mean - m2; s += d * d; }
    float var = blockSum256(s, red) * (1.f / 722.f);
    float inv = 1.f / sqrtf(var + 1e-5f);
    for (int i = tid; i < NDWT; i += 256) B1[i].x = (row[i] - mean) * inv;

    pool25<false>(row, pool, tid);
    __syncthreads();
    float msum = 0.f;
    for (int l = tid; l < NDWT; l += 256) {
        int pi = l - 12; pi = pi < 0 ? 0 : (pi > 697 ? 697 : pi);
        float m = pool[pi];
        msum += m;
        xc[l] = row[l] - m;
    }
    float m_all = blockSum256(msum, red) * (1.f / 722.f);
    __syncthreads();
    pool25<true>(xc, pool, tid);
    __syncthreads();
    float ssum = 0.f;
    for (int l = tid; l < NDWT; l += 256) {
        int pi = l - 12; pi = pi < 0 ? 0 : (pi > 697 ? 697 : pi);
        float sd = pool[pi] + 1e-5f;
        ssum += sd;
        acpL[l] = xc[l] / sd;
    }
    float s_all = blockSum256(ssum, red) * (1.f / 722.f);
    if (tid == 0) { stat[r] = m_all; stat[RTOT + r] = s_all; }
    for (int l = tid; l < KP1; l += 256) {
        if (l < NDWT) {
            float m = row[l] - xc[l];
            int pi = l - 12; pi = pi < 0 ? 0 : (pi > 697 ? 697 : pi);
            float sd = pool[pi] + 1e-5f;
            cent[baseP + l]      = f2bf(m - m_all);
            cent[CS + baseP + l] = f2bf(sd - s_all);
        } else { cent[baseP + l] = 0; cent[CS + baseP + l] = 0; }
    }
    __syncthreads();

    // ================= DC phase =================
    for (int i = tid; i < NDWT; i += 256) row[i] = dc0in[base + i];
    __syncthreads();
    pool25<false>(row, pool, tid);
    __syncthreads();
    float msum2 = 0.f;
    for (int l = tid; l < NDWT; l += 256) {
        int pi = l - 12; pi = pi < 0 ? 0 : (pi > 697 ? 697 : pi);
        float m = pool[pi];
        msum2 += m;
        xc[l] = row[l] - m;
    }
    float m_all2 = blockSum256(msum2, red) * (1.f / 722.f);
    __syncthreads();
    pool25<true>(xc, pool, tid);
    __syncthreads();
    float ssum2 = 0.f;
    for (int l = tid; l < NDWT; l += 256) {
        int pi = l - 12; pi = pi < 0 ? 0 : (pi > 697 ? 697 : pi);
        float sd = pool[pi] + 1e-5f;
        ssum2 += sd;
        B1[l].y = xc[l] / sd;
    }
    float s_all2 = blockSum256(ssum2, red) * (1.f / 722.f);
    if (tid == 0) { stat[2 * RTOT + r] = m_all2; stat[3 * RTOT + r] = s_all2; }
    for (int l = tid; l < KP1; l += 256) {
        if (l < NDWT) {
            float m = row[l] - xc[l];
            int pi = l - 12; pi = pi < 0 ? 0 : (pi > 697 ? 697 : pi);
            float sd = pool[pi] + 1e-5f;
            cent[2 * CS + baseP + l] = f2bf(m - m_all2);
            cent[3 * CS + baseP + l] = f2bf(sd - s_all2);
        } else { cent[2 * CS + baseP + l] = 0; cent[3 * CS + baseP + l] = 0; }
    }
    __syncthreads();

    // ================= FFT / top-k =================
    fft722_dev(B1, B2, Wt, W19s);
    for (int k = tid; k < 362; k += 256) {
        int m = (NDWT - k) % NDWT;
        f32x2 zk = B1[k], zm = B1[m];
        f32x2 ak = {0.5f * (zk.x + zm.x), 0.5f * (zk.y - zm.y)};
        f32x2 dk = {0.5f * (zk.y + zm.y), 0.5f * (zm.x - zk.x)};
        B1[k] = ak; B2[k] = dk;
        smag[k] = ak.x * ak.x + ak.y * ak.y;
        if (m != k) {
            f32x2 am = {0.5f * (zm.x + zk.x), 0.5f * (zm.y - zk.y)};
            f32x2 dm = {0.5f * (zm.y + zk.y), 0.5f * (zk.x - zm.x)};
            B1[m] = am; B2[m] = dm;
            smag[m] = am.x * am.x + am.y * am.y;
        }
    }
    __syncthreads();

    unsigned prefix = 0, rem = NFREQ;
    for (int shift = 24; shift >= 0; shift -= 8) {
        hist[tid] = 0;
        __syncthreads();
        unsigned hm = (shift == 24) ? 0u : (0xFFFFFFFFu << (shift + 8));
        for (int i = tid; i < NDWT; i += 256) {
            unsigned b = __float_as_uint(smag[i]);
            if ((b & hm) == prefix) atomicAdd(&hist[(b >> shift) & 255], 1u);
        }
        __syncthreads();
        if (tid < 64) {
            unsigned h0 = hist[tid * 4 + 0], h1 = hist[tid * 4 + 1];
            unsigned h2 = hist[tid * 4 + 2], h3 = hist[tid * 4 + 3];
            unsigned tot = h0 + h1 + h2 + h3;
            unsigned tinc = tot;
            #pragma unroll
            for (int off = 1; off < 64; off <<= 1) {
                unsigned v = __shfl_down(tinc, off, 64);
                tinc += (lane + off < 64) ? v : 0u;
            }
            unsigned tail = tinc - tot;
            unsigned S3 = tail + h3;
            unsigned S2 = S3 + h2;
            unsigned S1 = S2 + h1;
            unsigned S0 = S1 + h0;
            if (S0 >= rem && S1 < rem) { sh_digit = (unsigned)(tid * 4 + 0); sh_rem = rem - S1; }
            if (S1 >= rem && S2 < rem) { sh_digit = (unsigned)(tid * 4 + 1); sh_rem = rem - S2; }
            if (S2 >= rem && S3 < rem) { sh_digit = (unsigned)(tid * 4 + 2); sh_rem = rem - S3; }
            if (S3 >= rem && tail < rem) { sh_digit = (unsigned)(tid * 4 + 3); sh_rem = rem - tail; }
        }
        __syncthreads();
        prefix |= (sh_digit << shift);
        rem = sh_rem;
    }
    int c0 = tid * 3, cnt = 0;
    #pragma unroll
    for (int j = 0; j < 3; j++) {
        int i = c0 + j;
        if (i < NDWT && __float_as_uint(smag[i]) == prefix) cnt++;
    }
    suf[tid] = (unsigned)cnt;
    __syncthreads();
    if (tid < 64) {
        unsigned p0 = suf[tid * 4 + 0], p1 = suf[tid * 4 + 1];
        unsigned p2 = suf[tid * 4 + 2], p3 = suf[tid * 4 + 3];
        unsigned tot = p0 + p1 + p2 + p3;
        unsigned pinc = tot;
        #pragma unroll
        for (int off = 1; off < 64; off <<= 1) {
            unsigned v = __shfl_up(pinc, off, 64);
            pinc += (lane >= off) ? v : 0u;
        }
        unsigned head = pinc - tot;
        suf[tid * 4 + 0] = head;
        suf[tid * 4 + 1] = head + p0;
        suf[tid * 4 + 2] = head + p0 + p1;
        suf[tid * 4 + 3] = head + p0 + p1 + p2;
    }
    __syncthreads();
    int myexc = (int)suf[tid], o = 0;
    #pragma unroll
    for (int j = 0; j < 3; j++) {
        int i = c0 + j;
        if (i < NDWT) {
            unsigned b = __float_as_uint(smag[i]);
            int f = (b > prefix) ? 1 : 0;
            if (b == prefix) { if ((unsigned)(myexc + o) < rem) f = 1; o++; }
            smag[i] = f ? 1.f : 0.f;
        }
    }
    __syncthreads();

    // ================= real inverse FFT via 361-pt packing =================
    for (int k = tid; k < 361; k += 256) {
        int k2 = k + 361;
        int p1i = (NDWT - k) % NDWT;
        int p2i = NDWT - k2;
        float w1 = 0.5f * (smag[k] + smag[p1i]);
        float w2 = 0.5f * (smag[k2] + smag[p2i]);
        f32x2 a1 = B1[k], d1 = B2[k];
        f32x2 a2 = B1[k2], d2 = B2[k2];
        f32x2 m1 = { d1.x + w1 * 0.5f * (a1.x - d1.x), d1.y + w1 * 0.5f * (a1.y - d1.y) };
        f32x2 mB = { d2.x + w2 * 0.5f * (a2.x - d2.x), d2.y + w2 * 0.5f * (a2.y - d2.y) };
        f32x2 E = m1 + mB;
        f32x2 D = m1 - mB;
        f32x2 wc = Wt[k];
        f32x2 O = { D.x * wc.x + D.y * wc.y, D.y * wc.x - D.x * wc.y };
        B1[k] = f32x2{ E.x - O.y, -(E.y + O.x) };
    }
    __syncthreads();
    fft361_dev(B1, B2, Wt, W19s);

    // ================= xr-IWT epilogue =================
    const float inv722 = 1.f / 722.f;
    if (tid < 96) {
        int sub = tid / 6, c = 90 + tid % 6;
        xrbf[((size_t)r * 16 + sub) * 96 + c] = 0;
    }
    for (int t = tid; t < LSEQ; t += 256) {
        float sx = 0.f;
        if (t & 1) {
            int j0 = (t - 1) >> 1;
            #pragma unroll
            for (int i = 0; i < 3; i++) {
                int j = j0 + i;
                f32x2 z = B1[j >> 1];
                float dm = ((j & 1) ? -z.y : z.x) * inv722;
                sx += acpL[j] * c_lo[2 * i] + dm * c_hi[2 * i];
            }
        } else {
            int j0 = t >> 1;
            #pragma unroll
            for (int i = 0; i < 3; i++) {
                int j = j0 + i;
                f32x2 z = B1[j >> 1];
                float dm = ((j & 1) ? -z.y : z.x) * inv722;
                sx += acpL[j] * c_lo[2 * i + 1] + dm * c_hi[2 * i + 1];
            }
        }
        xrbf[((size_t)r * 16 + t / 90) * 96 + (t % 90)] = f2bf(sx);
    }
}

// ---------------- inverse DWT for mean/std heads (bf16 in, fp32 out) ----------------
__global__ __launch_bounds__(256) void iwt_heads_kernel(const unsigned short* __restrict__ heads,
                                                        float* __restrict__ out_mean,
                                                        float* __restrict__ out_std) {
    const int r = blockIdx.x;
    const int y = blockIdx.y;
    const int z = y / 3;
    const int t = (y % 3) * 256 + threadIdx.x;
    if (t >= 720) return;
    const size_t HR = (size_t)RTOT * NHEAD;
    const unsigned short* lp = heads + (size_t)z * HR + (size_t)r * NHEAD;
    const unsigned short* hp = heads + (size_t)(2 + z) * HR + (size_t)r * NHEAD;
    float* out = (z ? out_std : out_mean) + (size_t)r * 720;
    float s = 0.f;
    if (t & 1) {
        int j0 = (t - 1) >> 1;
        #pragma unroll
        for (int i = 0; i < 3; i++) s += bf2f(lp[j0 + i]) * c_lo[2 * i] + bf2f(hp[j0 + i]) * c_hi[2 * i];
    } else {
        int j0 = t >> 1;
        #pragma unroll
        for (int i = 0; i < 3; i++) s += bf2f(lp[j0 + i]) * c_lo[2 * i + 1] + bf2f(hp[j0 + i]) * c_hi[2 * i + 1];
    }
    out[t] = s;
}

// ---------------- z-batched bf16 MFMA GEMM, AM x 128 tile, BK=32, dbuf + COUNTED vmcnt ----------------
// AM = 128 or 256. 4 waves in 2x2; each wave owns (AM/2) x 64 output.
struct ZPtrs { const unsigned short* p[4]; };
template <int EPI, int AM>
__global__ __launch_bounds__(256) void mfma_gemm_z(
    const unsigned short* __restrict__ A, int lda, size_t zsA,
    ZPtrs Wz, int ldw,
    void* __restrict__ Cout, int ldc, size_t zsC, int Nc,
    const float* __restrict__ biasBase, const float* __restrict__ cbias,
    int Ksteps) {
    constexpr int MF  = AM / 32;     // m-frags per wave
    constexpr int AMC = AM / 64;     // A chunks per wave
    __shared__ unsigned short As[2][AM * 32];
    __shared__ unsigned short Bs[2][128 * 32];
    const int z = blockIdx.z;
    const unsigned short* Az = A + (size_t)z * zsA;
    const unsigned short* W = Wz.p[z];
    const int tid = threadIdx.x;
    const int lane = tid & 63, wid = tid >> 6;
    const int bm = blockIdx.x * AM, bn = blockIdx.y * 128;
    const int wr = (wid >> 1) * (AM / 2), wc = (wid & 1) * 64;
    f32x4 acc[MF][4] = {};
    const int srow = (lane >> 2);
    const int scol = (lane & 3) * 8;
    const unsigned short* ga[AMC];
    const unsigned short* gb[2];
    #pragma unroll
    for (int c = 0; c < AMC; c++)
        ga[c] = Az + (size_t)(bm + (wid * AMC + c) * 16 + srow) * lda + scol;
    #pragma unroll
    for (int c = 0; c < 2; c++)
        gb[c] = W + (size_t)(bn + (wid * 2 + c) * 16 + srow) * ldw + scol;

#define STAGE_GL(buf, ks) do { const int k0_ = (ks) * 32;                                              \
    _Pragma("unroll")                                                                                   \
    for (int c = 0; c < AMC; c++)                                                                       \
        __builtin_amdgcn_global_load_lds((const __attribute__((address_space(1))) unsigned int*)(ga[c] + k0_), \
            (__attribute__((address_space(3))) unsigned int*)(&As[buf][(wid * AMC + c) * 512]), 16, 0, 0);     \
    _Pragma("unroll")                                                                                   \
    for (int c = 0; c < 2; c++)                                                                         \
        __builtin_amdgcn_global_load_lds((const __attribute__((address_space(1))) unsigned int*)(gb[c] + k0_), \
            (__attribute__((address_space(3))) unsigned int*)(&Bs[buf][(wid * 2 + c) * 512]), 16, 0, 0);       \
    } while (0)

    STAGE_GL(0, 0);
    int cur = 0;
    const int kof = (lane >> 4) * 8;
    for (int ks = 0; ks < Ksteps; ks++) {
        if (ks + 1 < Ksteps) {
            STAGE_GL(cur ^ 1, ks + 1);
            if constexpr (AM == 128) asm volatile("s_waitcnt vmcnt(4)" ::: "memory");
            else                     asm volatile("s_waitcnt vmcnt(6)" ::: "memory");
        } else {
            asm volatile("s_waitcnt vmcnt(0)" ::: "memory");
        }
        __builtin_amdgcn_s_barrier();
        __builtin_amdgcn_sched_barrier(0);
        bf16x8 af[MF], bfr[4];
        #pragma unroll
        for (int m = 0; m < MF; m++)
            af[m] = *reinterpret_cast<const bf16x8*>(&As[cur][(wr + m * 16 + (lane & 15)) * 32 + kof]);
        #pragma unroll
        for (int n = 0; n < 4; n++)
            bfr[n] = *reinterpret_cast<const bf16x8*>(&Bs[cur][(wc + n * 16 + (lane & 15)) * 32 + kof]);
        #pragma unroll
        for (int m = 0; m < MF; m++)
            #pragma unroll
            for (int n = 0; n < 4; n++)
                acc[m][n] = __builtin_amdgcn_mfma_f32_16x16x32_bf16(af[m], bfr[n], acc[m][n], 0, 0, 0);
        __builtin_amdgcn_s_barrier();
        __builtin_amdgcn_sched_barrier(0);
        cur ^= 1;
    }
#undef STAGE_GL

    unsigned short* Cb = (unsigned short*)Cout + (size_t)z * zsC;
    float* Cf = (float*)Cout + (size_t)z * zsC;
    const int crow0 = bm + wr + (lane >> 4) * 4;
    const int ccol0 = bn + wc + (lane & 15);
    #pragma unroll
    for (int m = 0; m < MF; m++) {
        #pragma unroll
        for (int n = 0; n < 4; n++) {
            const int col = ccol0 + n * 16;
            if (col < Nc) {
                #pragma unroll
                for (int q = 0; q < 4; q++) {
                    const int row = crow0 + m * 16 + q;
                    float v = acc[m][n][q];
                    if (EPI == 0) {
                        Cb[(size_t)row * ldc + col] = f2bf(v);
                    } else if (EPI == 1) {
                        Cb[(size_t)row * ldc + col] = f2bf(fmaxf(v, 0.f));
                    } else if (EPI == 4) {
                        Cf[(size_t)row * ldc + col] = v + cbias[col];
                    } else { // 5: bf16 head out
                        float ob = biasBase[(size_t)z * RTOT + row];
                        if (z & 1) v = fmaxf(v + ob, 0.f) + 1e-5f;
                        else       v += ob;
                        Cb[(size_t)row * ldc + col] = f2bf(v);
                    }
                }
            }
        }
    }
}

extern "C" void kernel_launch(void* const* d_in, const int* in_sizes, int n_in,
                              void* d_out, int out_size, void* d_ws, size_t ws_size,
                              hipStream_t stream) {
    const float* x = (const float*)d_in[0];
    const float* latent_w = (const float*)d_in[1];
    int p0;
    const float* latent_b;
    if (n_in > 2 && in_sizes[2] == 512) { latent_b = (const float*)d_in[2]; p0 = 3; }
    else                                { latent_b = (const float*)d_in[18]; p0 = 2; }

    // ---------------- workspace layout ----------------
    char* wp = (char*)d_ws;
    auto alloc = [&](size_t bytes) { char* p = wp; wp += (bytes + 255) & ~(size_t)255; return p; };
    const size_t RN = (size_t)RTOT * NDWT;
    float* ac0b = (float*)alloc(RN * 4);
    float* dc0b = (float*)alloc(RN * 4);
    float* stat = (float*)alloc(4 * RTOT * 4);
    float2* Wtab = (float2*)alloc(NDWT * 8);
    unsigned short* cent  = (unsigned short*)alloc((size_t)4 * RTOT * KP1 * 2);
    unsigned short* xrbf  = (unsigned short*)alloc((size_t)131072 * 96 * 2);
    unsigned short* mlpB4 = (unsigned short*)alloc((size_t)4 * RTOT * 512 * 2);
    unsigned short* mlpA4 = (unsigned short*)alloc((size_t)4 * RTOT * 1024 * 2);
    unsigned short* mlpC4 = (unsigned short*)alloc((size_t)4 * RTOT * 512 * 2);
    unsigned short* heads = mlpB4;   // alias, lifetimes disjoint
    unsigned short *projW[4], *w1W[4], *w2W[4], *predW[4];
    for (int z = 0; z < 4; z++) {
        projW[z] = (unsigned short*)alloc((size_t)512 * KP1 * 2);
        w1W[z]   = (unsigned short*)alloc((size_t)1024 * 512 * 2);
        w2W[z]   = (unsigned short*)alloc((size_t)512 * 1024 * 2);
        predW[z] = (unsigned short*)alloc((size_t)384 * 512 * 2);
    }
    unsigned short* latwb = (unsigned short*)alloc((size_t)512 * 96 * 2);
    (void)ws_size;

    // ---------------- single batched weight convert + twiddle table ----------------
    CvtArgs ca;
    int si = 0;
    for (int z = 0; z < 4; z++) {
        int branch = z >> 1, isStd = z & 1, wb = p0 + branch * 8;
        ca.d[si++] = {(const float*)d_in[wb + isStd],         projW[z], 512, NDWT, 512, KP1};
        ca.d[si++] = {(const float*)d_in[wb + 2 + 2 * isStd], w1W[z], 1024, 512, 1024, 512};
        ca.d[si++] = {(const float*)d_in[wb + 3 + 2 * isStd], w2W[z], 512, 1024, 512, 1024};
        ca.d[si++] = {(const float*)d_in[wb + 6 + isStd],     predW[z], NHEAD, 512, 384, 512};
    }
    ca.d[16] = {latent_w, latwb, 512, 90, 512, 96};
    ca.wtab = Wtab;
    cvt_all_kernel<<<dim3(2048, 18), dim3(256), 0, stream>>>(ca);

    dwt_kernel<<<dim3(64, 23), dim3(256), 0, stream>>>(x, ac0b, dc0b);
    stats_fft_kernel<<<dim3(RTOT), dim3(256), 0, stream>>>(
        ac0b, dc0b, cent, stat, xrbf, (const f32x2*)Wtab);

    // emb = xr(131072 x 90) @ latent_w^T (512 x 90) + latent_b  (proven 128-tile path)
    float* out = (float*)d_out;
    ZPtrs Zl = {{latwb, latwb, latwb, latwb}};
    mfma_gemm_z<4, 128><<<dim3(1024, 4, 1), dim3(256), 0, stream>>>(
        xrbf, 96, 0, Zl, 96, out, 512, 0, 512, nullptr, latent_b, 3);

    // ---------------- 4 MLP chains, z-batched, 256x128 tiles ----------------
    ZPtrs Zp = {{projW[0], projW[1], projW[2], projW[3]}};
    ZPtrs Z1 = {{w1W[0], w1W[1], w1W[2], w1W[3]}};
    ZPtrs Z2 = {{w2W[0], w2W[1], w2W[2], w2W[3]}};
    ZPtrs Zh = {{predW[0], predW[1], predW[2], predW[3]}};
    mfma_gemm_z<0, 256><<<dim3(32, 4, 4), dim3(256), 0, stream>>>(
        cent, KP1, (size_t)RTOT * KP1, Zp, KP1, mlpB4, 512, (size_t)RTOT * 512, 512, nullptr, nullptr, KP1 / 32);
    mfma_gemm_z<1, 256><<<dim3(32, 8, 4), dim3(256), 0, stream>>>(
        mlpB4, 512, (size_t)RTOT * 512, Z1, 512, mlpA4, 1024, (size_t)RTOT * 1024, 1024, nullptr, nullptr, 16);
    mfma_gemm_z<0, 256><<<dim3(32, 4, 4), dim3(256), 0, stream>>>(
        mlpA4, 1024, (size_t)RTOT * 1024, Z2, 1024, mlpC4, 512, (size_t)RTOT * 512, 512, nullptr, nullptr, 32);
    mfma_gemm_z<5, 256><<<dim3(32, 3, 4), dim3(256), 0, stream>>>(
        mlpC4, 512, (size_t)RTOT * 512, Zh, 512, heads, NHEAD, (size_t)RTOT * NHEAD, NHEAD, stat, nullptr, 16);

    float* out_mean = out + (size_t)67108864;           // 64*128*16*512
    float* out_std  = out_mean + (size_t)5898240;       // 64*128*720
    iwt_heads_kernel<<<dim3(RTOT, 6), dim3(256), 0, stream>>>(heads, out_mean, out_std);
}

// Round 18
// 503.233 us; speedup vs baseline: 1.1853x; 1.1853x over previous
//
#include <hip/hip_runtime.h>
#include <cmath>

#define RTOT 8192        // B*C rows
#define NDWT 722         // SEQ_LEN/2+2
#define KP1  736         // NDWT padded to 32
#define LSEQ 1440
#define NHEAD 362        // PRED_LEN/2+2
#define NFREQ 362

typedef __bf16 bf16x8 __attribute__((ext_vector_type(8)));
typedef float f32x4 __attribute__((ext_vector_type(4)));
typedef float f32x2 __attribute__((ext_vector_type(2)));

__device__ __forceinline__ unsigned short f2bf(float f) {
    unsigned u = __float_as_uint(f);
    u += 0x7fffu + ((u >> 16) & 1u);
    return (unsigned short)(u >> 16);
}
__device__ __forceinline__ float bf2f(unsigned short u) {
    return __uint_as_float(((unsigned)u) << 16);
}

// complex MAC: s += a*w  (2x v_pk_fma_f32 via op_sel)
__device__ __forceinline__ void cmac(f32x2& s, f32x2 a, f32x2 w) {
    asm("v_pk_fma_f32 %0, %1, %2, %0 op_sel:[0,0,0] op_sel_hi:[0,1,1]\n\t"
        "v_pk_fma_f32 %0, %1, %2, %0 op_sel:[1,1,0] op_sel_hi:[1,0,1] neg_lo:[0,1,0]"
        : "+v"(s) : "v"(a), "v"(w));
}
// paired-conjugate MAC: s += a*w + b*conj(w), u = a+b, v = a-b
__device__ __forceinline__ void cmac2(f32x2& s, f32x2 u, f32x2 v, f32x2 w) {
    asm("v_pk_fma_f32 %0, %1, %3, %0 op_sel:[0,0,0] op_sel_hi:[1,0,1]\n\t"
        "v_pk_fma_f32 %0, %2, %3, %0 op_sel:[1,1,0] op_sel_hi:[0,1,1] neg_lo:[0,1,0]"
        : "+v"(s) : "v"(u), "v"(v), "v"(w));
}
// complex mul: r = a*b (v_pk_mul + v_pk_fma)
__device__ __forceinline__ f32x2 cmul(f32x2 a, f32x2 b) {
    f32x2 r;
    asm("v_pk_mul_f32 %0, %1, %2 op_sel:[0,0] op_sel_hi:[0,1]\n\t"
        "v_pk_fma_f32 %0, %1, %2, %0 op_sel:[1,1,0] op_sel_hi:[1,0,1] neg_lo:[0,1,0]"
        : "=&v"(r) : "v"(a), "v"(b));
    return r;
}

__constant__ float c_lo[6] = {0.035226291882100656f, -0.08544127388224149f, -0.13501102001039084f,
                              0.4598775021193313f, 0.8068915093133388f, 0.3326705529509569f};
__constant__ float c_hi[6] = {-0.3326705529509569f, 0.8068915093133388f, -0.4598775021193313f,
                              -0.13501102001039084f, 0.08544127388224149f, 0.035226291882100656f};

// ---------------- batched weight fp32 -> bf16 convert (4 elems/thread); y==17 computes twiddle table ----------------
struct CvtDesc { const float* src; unsigned short* dst; int N, K, Np, Kp; };
struct CvtArgs { CvtDesc d[17]; float2* wtab; };
__global__ __launch_bounds__(256) void cvt_all_kernel(CvtArgs a) {
    if (blockIdx.y == 17) {
        int m = blockIdx.x * 256 + threadIdx.x;
        if (m < NDWT) {
            double ang = -2.0 * 3.141592653589793238462643383279502884 * (double)m / (double)NDWT;
            a.wtab[m] = make_float2((float)cos(ang), (float)sin(ang));
        }
        return;
    }
    CvtDesc d = a.d[blockIdx.y];
    int tot = d.Np * d.Kp;
    int idx0 = (blockIdx.x * 256 + threadIdx.x) * 4;
    if (idx0 >= tot) return;
    #pragma unroll
    for (int q = 0; q < 4; q++) {
        int idx = idx0 + q;
        if (idx < tot) {
            int r = idx / d.Kp, c = idx - r * d.Kp;
            float v = (r < d.N && c < d.K) ? d.src[(size_t)r * d.K + c] : 0.f;
            d.dst[idx] = f2bf(v);
        }
    }
}

// ---------------- DWT via LDS transpose: x (64,1440,128) -> ac0, dc0 (8192,722) ----------------
__global__ __launch_bounds__(256) void dwt_kernel(const float* __restrict__ x,
                                                  float* __restrict__ ac0,
                                                  float* __restrict__ dc0) {
    __shared__ float xs[68][129];
    const int b = blockIdx.x;
    const int t0 = blockIdx.y * 32;
    const int tid = threadIdx.x;
    const int lbase = 2 * t0 - 4;
    for (int i = tid; i < 68 * 32; i += 256) {
        int ri = i >> 5;
        int c4 = (i & 31) * 4;
        int l = lbase + ri;
        float4 v = make_float4(0.f, 0.f, 0.f, 0.f);
        if (l >= 0 && l < LSEQ)
            v = *reinterpret_cast<const float4*>(&x[((size_t)b * LSEQ + l) * 128 + c4]);
        xs[ri][c4] = v.x; xs[ri][c4 + 1] = v.y; xs[ri][c4 + 2] = v.z; xs[ri][c4 + 3] = v.w;
    }
    __syncthreads();
    const int tt = tid & 31;
    const int t = t0 + tt;
    const int cw = tid >> 5;
    if (t < NDWT) {
        #pragma unroll 4
        for (int co = 0; co < 16; co++) {
            int c = co * 8 + cw;
            float slo = 0.f, shi = 0.f;
            #pragma unroll
            for (int j = 0; j < 6; j++) {
                float v = xs[2 * tt + 5 - j][c];
                slo += v * c_lo[j];
                shi += v * c_hi[j];
            }
            size_t o = ((size_t)b * 128 + c) * NDWT + t;
            ac0[o] = slo;
            dc0[o] = shi;
        }
    }
}

__device__ __forceinline__ float blockSum256(float v, float* red) {
    #pragma unroll
    for (int o = 32; o > 0; o >>= 1) v += __shfl_down(v, o, 64);
    int lane = threadIdx.x & 63, wid = threadIdx.x >> 6;
    __syncthreads();
    if (lane == 0) red[wid] = v;
    __syncthreads();
    return red[0] + red[1] + red[2] + red[3];
}

// sliding-window 25-tap mean over rowv[0..721] -> pool[0..697]; 3 outputs/thread
template <bool ABS>
__device__ __forceinline__ void pool25(const float* rowv, float* pool, int tid) {
    int i0 = tid * 3;
    if (i0 < 698) {
        float s25 = 0.f;
        #pragma unroll
        for (int j = 0; j < 25; j++) { float v = rowv[i0 + j]; s25 += ABS ? fabsf(v) : v; }
        pool[i0] = s25 * (1.f / 25.f);
        #pragma unroll
        for (int qq = 1; qq < 3; qq++) {
            int i = i0 + qq;
            if (i < 698) {
                float vin = rowv[i + 24], vout = rowv[i - 1];
                s25 += (ABS ? fabsf(vin) : vin) - (ABS ? fabsf(vout) : vout);
                pool[i] = s25 * (1.f / 25.f);
            }
        }
    }
}

// ---------------- FFT-722, IN-PLACE, group-restructured + conjugate-pair DFT-19 ----------------
__device__ void fft722_dev(f32x2* X, f32x2* T, const f32x2* Wt, const f32x2* W19) {
    const int tid = threadIdx.x;
    if (tid < 190) {
        const int c = tid / 38;
        const int g = tid - c * 38;
        const int p = (g >= 19) ? 1 : 0;
        const int rr = g - 19 * p;
        const int t0 = c * 4;
        const int nt = (c == 4) ? 3 : 4;
        const f32x2* xp = X + 2 * rr + p;
        f32x2 st[4], w[4], s[4];
        f32x2 a0 = xp[0];
        #pragma unroll
        for (int i = 0; i < 4; i++) {
            int ti = t0 + i; if (ti > 18) ti = 0;
            st[i] = W19[ti];
            w[i] = st[i];
            s[i] = a0;
        }
        #pragma unroll
        for (int m = 1; m <= 9; m++) {
            f32x2 a = xp[38 * m];
            f32x2 b = xp[38 * (19 - m)];
            f32x2 u = a + b, v = a - b;
            #pragma unroll
            for (int i = 0; i < 4; i++) {
                cmac2(s[i], u, v, w[i]);
                if (m < 9) w[i] = cmul(w[i], st[i]);
            }
        }
        int m0 = rr * t0;
        f32x2* Tp = T + p * 361 + rr * 19 + t0;
        #pragma unroll
        for (int i = 0; i < 4; i++) {
            if (i < nt) Tp[i] = cmul(s[i], Wt[2 * m0]);
            m0 += rr;
        }
    }
    __syncthreads();
    if (tid < 190) {
        const int c = tid / 38;
        const int g = tid - c * 38;
        const int p = (g >= 19) ? 1 : 0;
        const int t = g - 19 * p;
        const int jj0 = c * 4;
        const int nj = (c == 4) ? 3 : 4;
        const f32x2* Ap = T + p * 361 + t;
        f32x2 st[4], w[4], s[4];
        f32x2 a0 = Ap[0];
        #pragma unroll
        for (int i = 0; i < 4; i++) {
            int jj = jj0 + i; if (jj > 18) jj = 0;
            st[i] = W19[jj];
            w[i] = st[i];
            s[i] = a0;
        }
        #pragma unroll
        for (int m = 1; m <= 9; m++) {
            f32x2 a = Ap[19 * m];
            f32x2 b = Ap[19 * (19 - m)];
            f32x2 u = a + b, v = a - b;
            #pragma unroll
            for (int i = 0; i < 4; i++) {
                cmac2(s[i], u, v, w[i]);
                if (m < 9) w[i] = cmul(w[i], st[i]);
            }
        }
        f32x2* Xp = X + p * 361;
        #pragma unroll
        for (int i = 0; i < 4; i++) {
            int jj = jj0 + i;
            if (i < nj) Xp[t + 19 * jj] = s[i];
        }
    }
    __syncthreads();
    for (int k = tid; k < 361; k += 256) {
        f32x2 e = X[k], o = X[361 + k], w = Wt[k];
        f32x2 tt = {0.f, 0.f};
        cmac(tt, o, w);
        X[k] = e + tt;
        X[361 + k] = e - tt;
    }
    __syncthreads();
}

// ---------------- FFT-361 (19 x 19), X[0..360] in place, scratch T[0..360] ----------------
__device__ void fft361_dev(f32x2* X, f32x2* T, const f32x2* Wt, const f32x2* W19) {
    const int tid = threadIdx.x;
    if (tid < 95) {
        const int a = tid / 5;
        const int ch = tid % 5;
        const int t0 = ch * 4;
        const int nt = (ch == 4) ? 3 : 4;
        const f32x2* xp = X + a;
        f32x2 st[4], w[4], s[4];
        f32x2 a0 = xp[0];
        #pragma unroll
        for (int i = 0; i < 4; i++) {
            int ti = t0 + i; if (ti > 18) ti = 0;
            st[i] = W19[ti];
            w[i] = st[i];
            s[i] = a0;
        }
        #pragma unroll
        for (int m = 1; m <= 9; m++) {
            f32x2 aa = xp[19 * m];
            f32x2 bb = xp[19 * (19 - m)];
            f32x2 u = aa + bb, v = aa - bb;
            #pragma unroll
            for (int i = 0; i < 4; i++) {
                cmac2(s[i], u, v, w[i]);
                if (m < 9) w[i] = cmul(w[i], st[i]);
            }
        }
        int m0 = a * t0;
        f32x2* Tp = T + a * 19 + t0;
        #pragma unroll
        for (int i = 0; i < 4; i++) {
            if (i < nt) Tp[i] = cmul(s[i], Wt[2 * m0]);
            m0 += a;
        }
    }
    __syncthreads();
    if (tid < 95) {
        const int t = tid / 5;
        const int ch = tid % 5;
        const int c0 = ch * 4;
        const int nc = (ch == 4) ? 3 : 4;
        const f32x2* Ap = T + t;
        f32x2 st[4], w[4], s[4];
        f32x2 a0 = Ap[0];
        #pragma unroll
        for (int i = 0; i < 4; i++) {
            int cc = c0 + i; if (cc > 18) cc = 0;
            st[i] = W19[cc];
            w[i] = st[i];
            s[i] = a0;
        }
        #pragma unroll
        for (int m = 1; m <= 9; m++) {
            f32x2 aa = Ap[19 * m];
            f32x2 bb = Ap[19 * (19 - m)];
            f32x2 u = aa + bb, v = aa - bb;
            #pragma unroll
            for (int i = 0; i < 4; i++) {
                cmac2(s[i], u, v, w[i]);
                if (m < 9) w[i] = cmul(w[i], st[i]);
            }
        }
        #pragma unroll
        for (int i = 0; i < 4; i++) {
            int cc = c0 + i;
            if (i < nc) X[t + 19 * cc] = s[i];
        }
    }
    __syncthreads();
}

// ---------------- FUSED per-row: stats + packed FFT + top-k mix + real-iFFT(361) + xr-IWT ----------------
__global__ __launch_bounds__(256) void stats_fft_kernel(
    const float* __restrict__ ac0in,
    const float* __restrict__ dc0in,
    unsigned short* __restrict__ cent,  // [4][RTOT][KP1]
    float* __restrict__ stat,           // [4][RTOT]
    unsigned short* __restrict__ xrbf,  // [RTOT*16][96]
    const f32x2* __restrict__ Wtab) {
    __shared__ f32x2 Wt[NDWT];
    __shared__ f32x2 W19s[19];
    __shared__ f32x2 B1[NDWT];
    __shared__ float acpL[NDWT];
    __shared__ __align__(16) char arena[8704];
    __shared__ unsigned hist[256];
    __shared__ unsigned suf[256];
    __shared__ unsigned sh_digit, sh_rem;
    f32x2* B2   = (f32x2*)arena;
    float* smag = (float*)(arena + 5776);
    float* row  = (float*)arena;
    float* xc   = (float*)(arena + 2888);
    float* pool = (float*)(arena + 5776);
    float* red  = (float*)(arena + 8568);
    const int r = blockIdx.x, tid = threadIdx.x;
    const int lane = tid & 63;
    const size_t base = (size_t)r * NDWT;
    const size_t baseP = (size_t)r * KP1;
    const size_t CS = (size_t)RTOT * KP1;

    for (int i = tid; i < NDWT; i += 256) Wt[i] = Wtab[i];
    if (tid < 19) W19s[tid] = Wtab[38 * tid];

    // ================= AC phase =================
    for (int i = tid; i < NDWT; i += 256) row[i] = ac0in[base + i];
    __syncthreads();
    float s = 0.f;
    for (int i = tid; i < NDWT; i += 256) s += row[i];
    float mean = blockSum256(s, red) * (1.f / 722.f);
    s = 0.f;
    for (int i = tid; i < NDWT; i += 256) s += row[i] - mean;
    float m2 = blockSum256(s, red) * (1.f / 722.f);
    s = 0.f;
    for (int i = tid; i < NDWT; i += 256) { float d = row[i] - mean - m2; s += d * d; }
    float var = blockSum256(s, red) * (1.f / 722.f);
    float inv = 1.f / sqrtf(var + 1e-5f);
    for (int i = tid; i < NDWT; i += 256) B1[i].x = (row[i] - mean) * inv;

    pool25<false>(row, pool, tid);
    __syncthreads();
    float msum = 0.f;
    for (int l = tid; l < NDWT; l += 256) {
        int pi = l - 12; pi = pi < 0 ? 0 : (pi > 697 ? 697 : pi);
        float m = pool[pi];
        msum += m;
        xc[l] = row[l] - m;
    }
    float m_all = blockSum256(msum, red) * (1.f / 722.f);
    __syncthreads();
    pool25<true>(xc, pool, tid);
    __syncthreads();
    float ssum = 0.f;
    for (int l = tid; l < NDWT; l += 256) {
        int pi = l - 12; pi = pi < 0 ? 0 : (pi > 697 ? 697 : pi);
        float sd = pool[pi] + 1e-5f;
        ssum += sd;
        acpL[l] = xc[l] / sd;
    }
    float s_all = blockSum256(ssum, red) * (1.f / 722.f);
    if (tid == 0) { stat[r] = m_all; stat[RTOT + r] = s_all; }
    for (int l = tid; l < KP1; l += 256) {
        if (l < NDWT) {
            float m = row[l] - xc[l];
            int pi = l - 12; pi = pi < 0 ? 0 : (pi > 697 ? 697 : pi);
            float sd = pool[pi] + 1e-5f;
            cent[baseP + l]      = f2bf(m - m_all);
            cent[CS + baseP + l] = f2bf(sd - s_all);
        } else { cent[baseP + l] = 0; cent[CS + baseP + l] = 0; }
    }
    __syncthreads();

    // ================= DC phase =================
    for (int i = tid; i < NDWT; i += 256) row[i] = dc0in[base + i];
    __syncthreads();
    pool25<false>(row, pool, tid);
    __syncthreads();
    float msum2 = 0.f;
    for (int l = tid; l < NDWT; l += 256) {
        int pi = l - 12; pi = pi < 0 ? 0 : (pi > 697 ? 697 : pi);
        float m = pool[pi];
        msum2 += m;
        xc[l] = row[l] - m;
    }
    float m_all2 = blockSum256(msum2, red) * (1.f / 722.f);
    __syncthreads();
    pool25<true>(xc, pool, tid);
    __syncthreads();
    float ssum2 = 0.f;
    for (int l = tid; l < NDWT; l += 256) {
        int pi = l - 12; pi = pi < 0 ? 0 : (pi > 697 ? 697 : pi);
        float sd = pool[pi] + 1e-5f;
        ssum2 += sd;
        B1[l].y = xc[l] / sd;
    }
    float s_all2 = blockSum256(ssum2, red) * (1.f / 722.f);
    if (tid == 0) { stat[2 * RTOT + r] = m_all2; stat[3 * RTOT + r] = s_all2; }
    for (int l = tid; l < KP1; l += 256) {
        if (l < NDWT) {
            float m = row[l] - xc[l];
            int pi = l - 12; pi = pi < 0 ? 0 : (pi > 697 ? 697 : pi);
            float sd = pool[pi] + 1e-5f;
            cent[2 * CS + baseP + l] = f2bf(m - m_all2);
            cent[3 * CS + baseP + l] = f2bf(sd - s_all2);
        } else { cent[2 * CS + baseP + l] = 0; cent[3 * CS + baseP + l] = 0; }
    }
    __syncthreads();

    // ================= FFT / top-k =================
    fft722_dev(B1, B2, Wt, W19s);
    for (int k = tid; k < 362; k += 256) {
        int m = (NDWT - k) % NDWT;
        f32x2 zk = B1[k], zm = B1[m];
        f32x2 ak = {0.5f * (zk.x + zm.x), 0.5f * (zk.y - zm.y)};
        f32x2 dk = {0.5f * (zk.y + zm.y), 0.5f * (zm.x - zk.x)};
        B1[k] = ak; B2[k] = dk;
        smag[k] = ak.x * ak.x + ak.y * ak.y;
        if (m != k) {
            f32x2 am = {0.5f * (zm.x + zk.x), 0.5f * (zm.y - zk.y)};
            f32x2 dm = {0.5f * (zm.y + zk.y), 0.5f * (zk.x - zm.x)};
            B1[m] = am; B2[m] = dm;
            smag[m] = am.x * am.x + am.y * am.y;
        }
    }
    __syncthreads();

    unsigned prefix = 0, rem = NFREQ;
    for (int shift = 24; shift >= 0; shift -= 8) {
        hist[tid] = 0;
        __syncthreads();
        unsigned hm = (shift == 24) ? 0u : (0xFFFFFFFFu << (shift + 8));
        for (int i = tid; i < NDWT; i += 256) {
            unsigned b = __float_as_uint(smag[i]);
            if ((b & hm) == prefix) atomicAdd(&hist[(b >> shift) & 255], 1u);
        }
        __syncthreads();
        if (tid < 64) {
            unsigned h0 = hist[tid * 4 + 0], h1 = hist[tid * 4 + 1];
            unsigned h2 = hist[tid * 4 + 2], h3 = hist[tid * 4 + 3];
            unsigned tot = h0 + h1 + h2 + h3;
            unsigned tinc = tot;
            #pragma unroll
            for (int off = 1; off < 64; off <<= 1) {
                unsigned v = __shfl_down(tinc, off, 64);
                tinc += (lane + off < 64) ? v : 0u;
            }
            unsigned tail = tinc - tot;
            unsigned S3 = tail + h3;
            unsigned S2 = S3 + h2;
            unsigned S1 = S2 + h1;
            unsigned S0 = S1 + h0;
            if (S0 >= rem && S1 < rem) { sh_digit = (unsigned)(tid * 4 + 0); sh_rem = rem - S1; }
            if (S1 >= rem && S2 < rem) { sh_digit = (unsigned)(tid * 4 + 1); sh_rem = rem - S2; }
            if (S2 >= rem && S3 < rem) { sh_digit = (unsigned)(tid * 4 + 2); sh_rem = rem - S3; }
            if (S3 >= rem && tail < rem) { sh_digit = (unsigned)(tid * 4 + 3); sh_rem = rem - tail; }
        }
        __syncthreads();
        prefix |= (sh_digit << shift);
        rem = sh_rem;
    }
    int c0 = tid * 3, cnt = 0;
    #pragma unroll
    for (int j = 0; j < 3; j++) {
        int i = c0 + j;
        if (i < NDWT && __float_as_uint(smag[i]) == prefix) cnt++;
    }
    suf[tid] = (unsigned)cnt;
    __syncthreads();
    if (tid < 64) {
        unsigned p0 = suf[tid * 4 + 0], p1 = suf[tid * 4 + 1];
        unsigned p2 = suf[tid * 4 + 2], p3 = suf[tid * 4 + 3];
        unsigned tot = p0 + p1 + p2 + p3;
        unsigned pinc = tot;
        #pragma unroll
        for (int off = 1; off < 64; off <<= 1) {
            unsigned v = __shfl_up(pinc, off, 64);
            pinc += (lane >= off) ? v : 0u;
        }
        unsigned head = pinc - tot;
        suf[tid * 4 + 0] = head;
        suf[tid * 4 + 1] = head + p0;
        suf[tid * 4 + 2] = head + p0 + p1;
        suf[tid * 4 + 3] = head + p0 + p1 + p2;
    }
    __syncthreads();
    int myexc = (int)suf[tid], o = 0;
    #pragma unroll
    for (int j = 0; j < 3; j++) {
        int i = c0 + j;
        if (i < NDWT) {
            unsigned b = __float_as_uint(smag[i]);
            int f = (b > prefix) ? 1 : 0;
            if (b == prefix) { if ((unsigned)(myexc + o) < rem) f = 1; o++; }
            smag[i] = f ? 1.f : 0.f;
        }
    }
    __syncthreads();

    // ================= real inverse FFT via 361-pt packing =================
    for (int k = tid; k < 361; k += 256) {
        int k2 = k + 361;
        int p1i = (NDWT - k) % NDWT;
        int p2i = NDWT - k2;
        float w1 = 0.5f * (smag[k] + smag[p1i]);
        float w2 = 0.5f * (smag[k2] + smag[p2i]);
        f32x2 a1 = B1[k], d1 = B2[k];
        f32x2 a2 = B1[k2], d2 = B2[k2];
        f32x2 m1 = { d1.x + w1 * 0.5f * (a1.x - d1.x), d1.y + w1 * 0.5f * (a1.y - d1.y) };
        f32x2 mB = { d2.x + w2 * 0.5f * (a2.x - d2.x), d2.y + w2 * 0.5f * (a2.y - d2.y) };
        f32x2 E = m1 + mB;
        f32x2 D = m1 - mB;
        f32x2 wc = Wt[k];
        f32x2 O = { D.x * wc.x + D.y * wc.y, D.y * wc.x - D.x * wc.y };
        B1[k] = f32x2{ E.x - O.y, -(E.y + O.x) };
    }
    __syncthreads();
    fft361_dev(B1, B2, Wt, W19s);

    // ================= xr-IWT epilogue =================
    const float inv722 = 1.f / 722.f;
    if (tid < 96) {
        int sub = tid / 6, c = 90 + tid % 6;
        xrbf[((size_t)r * 16 + sub) * 96 + c] = 0;
    }
    for (int t = tid; t < LSEQ; t += 256) {
        float sx = 0.f;
        if (t & 1) {
            int j0 = (t - 1) >> 1;
            #pragma unroll
            for (int i = 0; i < 3; i++) {
                int j = j0 + i;
                f32x2 z = B1[j >> 1];
                float dm = ((j & 1) ? -z.y : z.x) * inv722;
                sx += acpL[j] * c_lo[2 * i] + dm * c_hi[2 * i];
            }
        } else {
            int j0 = t >> 1;
            #pragma unroll
            for (int i = 0; i < 3; i++) {
                int j = j0 + i;
                f32x2 z = B1[j >> 1];
                float dm = ((j & 1) ? -z.y : z.x) * inv722;
                sx += acpL[j] * c_lo[2 * i + 1] + dm * c_hi[2 * i + 1];
            }
        }
        xrbf[((size_t)r * 16 + t / 90) * 96 + (t % 90)] = f2bf(sx);
    }
}

// ---------------- inverse DWT for mean/std heads (bf16 in, fp32 out) ----------------
__global__ __launch_bounds__(256) void iwt_heads_kernel(const unsigned short* __restrict__ heads,
                                                        float* __restrict__ out_mean,
                                                        float* __restrict__ out_std) {
    const int r = blockIdx.x;
    const int y = blockIdx.y;
    const int z = y / 3;
    const int t = (y % 3) * 256 + threadIdx.x;
    if (t >= 720) return;
    const size_t HR = (size_t)RTOT * NHEAD;
    const unsigned short* lp = heads + (size_t)z * HR + (size_t)r * NHEAD;
    const unsigned short* hp = heads + (size_t)(2 + z) * HR + (size_t)r * NHEAD;
    float* out = (z ? out_std : out_mean) + (size_t)r * 720;
    float s = 0.f;
    if (t & 1) {
        int j0 = (t - 1) >> 1;
        #pragma unroll
        for (int i = 0; i < 3; i++) s += bf2f(lp[j0 + i]) * c_lo[2 * i] + bf2f(hp[j0 + i]) * c_hi[2 * i];
    } else {
        int j0 = t >> 1;
        #pragma unroll
        for (int i = 0; i < 3; i++) s += bf2f(lp[j0 + i]) * c_lo[2 * i + 1] + bf2f(hp[j0 + i]) * c_hi[2 * i + 1];
    }
    out[t] = s;
}

// ---------------- z-batched bf16 MFMA GEMM, 128x128 tile, BK=32, dbuf + COUNTED vmcnt (T4) ----------------
struct ZPtrs { const unsigned short* p[4]; };
template <int EPI>
__global__ __launch_bounds__(256) void mfma_gemm_z(
    const unsigned short* __restrict__ A, int lda, size_t zsA,
    ZPtrs Wz, int ldw,
    void* __restrict__ Cout, int ldc, size_t zsC, int Nc,
    const float* __restrict__ biasBase, const float* __restrict__ cbias,
    int Ksteps) {
    __shared__ unsigned short As[2][128 * 32];
    __shared__ unsigned short Bs[2][128 * 32];
    const int z = blockIdx.z;
    const unsigned short* Az = A + (size_t)z * zsA;
    const unsigned short* W = Wz.p[z];
    const int tid = threadIdx.x;
    const int lane = tid & 63, wid = tid >> 6;
    const int bm = blockIdx.x * 128, bn = blockIdx.y * 128;
    const int wr = (wid >> 1) * 64, wc = (wid & 1) * 64;
    f32x4 acc[4][4] = {};
    const int srow = (lane >> 2);
    const int scol = (lane & 3) * 8;
    const int ch0 = wid * 2, ch1 = wid * 2 + 1;
    const unsigned short* ga0 = Az + (size_t)(bm + ch0 * 16 + srow) * lda + scol;
    const unsigned short* ga1 = Az + (size_t)(bm + ch1 * 16 + srow) * lda + scol;
    const unsigned short* gb0 = W + (size_t)(bn + ch0 * 16 + srow) * ldw + scol;
    const unsigned short* gb1 = W + (size_t)(bn + ch1 * 16 + srow) * ldw + scol;

#define STAGE_GL(buf, ks) do { const int k0_ = (ks) * 32;                                      \
    __builtin_amdgcn_global_load_lds((const __attribute__((address_space(1))) unsigned int*)(ga0 + k0_), \
        (__attribute__((address_space(3))) unsigned int*)(&As[buf][ch0 * 512]), 16, 0, 0);     \
    __builtin_amdgcn_global_load_lds((const __attribute__((address_space(1))) unsigned int*)(gb0 + k0_), \
        (__attribute__((address_space(3))) unsigned int*)(&Bs[buf][ch0 * 512]), 16, 0, 0);     \
    __builtin_amdgcn_global_load_lds((const __attribute__((address_space(1))) unsigned int*)(ga1 + k0_), \
        (__attribute__((address_space(3))) unsigned int*)(&As[buf][ch1 * 512]), 16, 0, 0);     \
    __builtin_amdgcn_global_load_lds((const __attribute__((address_space(1))) unsigned int*)(gb1 + k0_), \
        (__attribute__((address_space(3))) unsigned int*)(&Bs[buf][ch1 * 512]), 16, 0, 0);     \
    } while (0)

    STAGE_GL(0, 0);
    int cur = 0;
    const int kof = (lane >> 4) * 8;
    for (int ks = 0; ks < Ksteps; ks++) {
        if (ks + 1 < Ksteps) {
            STAGE_GL(cur ^ 1, ks + 1);
            asm volatile("s_waitcnt vmcnt(4)" ::: "memory");
        } else {
            asm volatile("s_waitcnt vmcnt(0)" ::: "memory");
        }
        __builtin_amdgcn_s_barrier();
        __builtin_amdgcn_sched_barrier(0);
        bf16x8 af[4], bfr[4];
        #pragma unroll
        for (int m = 0; m < 4; m++)
            af[m] = *reinterpret_cast<const bf16x8*>(&As[cur][(wr + m * 16 + (lane & 15)) * 32 + kof]);
        #pragma unroll
        for (int n = 0; n < 4; n++)
            bfr[n] = *reinterpret_cast<const bf16x8*>(&Bs[cur][(wc + n * 16 + (lane & 15)) * 32 + kof]);
        #pragma unroll
        for (int m = 0; m < 4; m++)
            #pragma unroll
            for (int n = 0; n < 4; n++)
                acc[m][n] = __builtin_amdgcn_mfma_f32_16x16x32_bf16(af[m], bfr[n], acc[m][n], 0, 0, 0);
        __builtin_amdgcn_s_barrier();
        __builtin_amdgcn_sched_barrier(0);
        cur ^= 1;
    }
#undef STAGE_GL

    unsigned short* Cb = (unsigned short*)Cout + (size_t)z * zsC;
    float* Cf = (float*)Cout + (size_t)z * zsC;
    const int crow0 = bm + wr + (lane >> 4) * 4;
    const int ccol0 = bn + wc + (lane & 15);
    #pragma unroll
    for (int m = 0; m < 4; m++) {
        #pragma unroll
        for (int n = 0; n < 4; n++) {
            const int col = ccol0 + n * 16;
            if (col < Nc) {
                #pragma unroll
                for (int q = 0; q < 4; q++) {
                    const int row = crow0 + m * 16 + q;
                    float v = acc[m][n][q];
                    if (EPI == 0) {
                        Cb[(size_t)row * ldc + col] = f2bf(v);
                    } else if (EPI == 1) {
                        Cb[(size_t)row * ldc + col] = f2bf(fmaxf(v, 0.f));
                    } else if (EPI == 4) {
                        Cf[(size_t)row * ldc + col] = v + cbias[col];
                    } else { // 5: bf16 head out
                        float ob = biasBase[(size_t)z * RTOT + row];
                        if (z & 1) v = fmaxf(v + ob, 0.f) + 1e-5f;
                        else       v += ob;
                        Cb[(size_t)row * ldc + col] = f2bf(v);
                    }
                }
            }
        }
    }
}

extern "C" void kernel_launch(void* const* d_in, const int* in_sizes, int n_in,
                              void* d_out, int out_size, void* d_ws, size_t ws_size,
                              hipStream_t stream) {
    const float* x = (const float*)d_in[0];
    const float* latent_w = (const float*)d_in[1];
    int p0;
    const float* latent_b;
    if (n_in > 2 && in_sizes[2] == 512) { latent_b = (const float*)d_in[2]; p0 = 3; }
    else                                { latent_b = (const float*)d_in[18]; p0 = 2; }

    // ---------------- workspace layout ----------------
    char* wp = (char*)d_ws;
    auto alloc = [&](size_t bytes) { char* p = wp; wp += (bytes + 255) & ~(size_t)255; return p; };
    const size_t RN = (size_t)RTOT * NDWT;
    float* ac0b = (float*)alloc(RN * 4);
    float* dc0b = (float*)alloc(RN * 4);
    float* stat = (float*)alloc(4 * RTOT * 4);
    float2* Wtab = (float2*)alloc(NDWT * 8);
    unsigned short* cent  = (unsigned short*)alloc((size_t)4 * RTOT * KP1 * 2);
    unsigned short* xrbf  = (unsigned short*)alloc((size_t)131072 * 96 * 2);
    unsigned short* mlpB4 = (unsigned short*)alloc((size_t)4 * RTOT * 512 * 2);
    unsigned short* mlpA4 = (unsigned short*)alloc((size_t)4 * RTOT * 1024 * 2);
    unsigned short* mlpC4 = (unsigned short*)alloc((size_t)4 * RTOT * 512 * 2);
    unsigned short* heads = mlpB4;   // alias, lifetimes disjoint
    unsigned short *projW[4], *w1W[4], *w2W[4], *predW[4];
    for (int z = 0; z < 4; z++) {
        projW[z] = (unsigned short*)alloc((size_t)512 * KP1 * 2);
        w1W[z]   = (unsigned short*)alloc((size_t)1024 * 512 * 2);
        w2W[z]   = (unsigned short*)alloc((size_t)512 * 1024 * 2);
        predW[z] = (unsigned short*)alloc((size_t)384 * 512 * 2);
    }
    unsigned short* latwb = (unsigned short*)alloc((size_t)512 * 96 * 2);
    (void)ws_size;

    // ---------------- single batched weight convert + twiddle table ----------------
    CvtArgs ca;
    int si = 0;
    for (int z = 0; z < 4; z++) {
        int branch = z >> 1, isStd = z & 1, wb = p0 + branch * 8;
        ca.d[si++] = {(const float*)d_in[wb + isStd],         projW[z], 512, NDWT, 512, KP1};
        ca.d[si++] = {(const float*)d_in[wb + 2 + 2 * isStd], w1W[z], 1024, 512, 1024, 512};
        ca.d[si++] = {(const float*)d_in[wb + 3 + 2 * isStd], w2W[z], 512, 1024, 512, 1024};
        ca.d[si++] = {(const float*)d_in[wb + 6 + isStd],     predW[z], NHEAD, 512, 384, 512};
    }
    ca.d[16] = {latent_w, latwb, 512, 90, 512, 96};
    ca.wtab = Wtab;
    cvt_all_kernel<<<dim3(512, 18), dim3(256), 0, stream>>>(ca);

    dwt_kernel<<<dim3(64, 23), dim3(256), 0, stream>>>(x, ac0b, dc0b);
    stats_fft_kernel<<<dim3(RTOT), dim3(256), 0, stream>>>(
        ac0b, dc0b, cent, stat, xrbf, (const f32x2*)Wtab);

    // emb = xr(131072 x 90) @ latent_w^T (512 x 90) + latent_b
    float* out = (float*)d_out;
    ZPtrs Zl = {{latwb, latwb, latwb, latwb}};
    mfma_gemm_z<4><<<dim3(1024, 4, 1), dim3(256), 0, stream>>>(
        xrbf, 96, 0, Zl, 96, out, 512, 0, 512, nullptr, latent_b, 3);

    // ---------------- 4 MLP chains, z-batched, 128x128 tiles (proven) ----------------
    ZPtrs Zp = {{projW[0], projW[1], projW[2], projW[3]}};
    ZPtrs Z1 = {{w1W[0], w1W[1], w1W[2], w1W[3]}};
    ZPtrs Z2 = {{w2W[0], w2W[1], w2W[2], w2W[3]}};
    ZPtrs Zh = {{predW[0], predW[1], predW[2], predW[3]}};
    mfma_gemm_z<0><<<dim3(64, 4, 4), dim3(256), 0, stream>>>(
        cent, KP1, (size_t)RTOT * KP1, Zp, KP1, mlpB4, 512, (size_t)RTOT * 512, 512, nullptr, nullptr, KP1 / 32);
    mfma_gemm_z<1><<<dim3(64, 8, 4), dim3(256), 0, stream>>>(
        mlpB4, 512, (size_t)RTOT * 512, Z1, 512, mlpA4, 1024, (size_t)RTOT * 1024, 1024, nullptr, nullptr, 16);
    mfma_gemm_z<0><<<dim3(64, 4, 4), dim3(256), 0, stream>>>(
        mlpA4, 1024, (size_t)RTOT * 1024, Z2, 1024, mlpC4, 512, (size_t)RTOT * 512, 512, nullptr, nullptr, 32);
    mfma_gemm_z<5><<<dim3(64, 3, 4), dim3(256), 0, stream>>>(
        mlpC4, 512, (size_t)RTOT * 512, Zh, 512, heads, NHEAD, (size_t)RTOT * NHEAD, NHEAD, stat, nullptr, 16);

    float* out_mean = out + (size_t)67108864;           // 64*128*16*512
    float* out_std  = out_mean + (size_t)5898240;       // 64*128*720
    iwt_heads_kernel<<<dim3(RTOT, 6), dim3(256), 0, stream>>>(heads, out_mean, out_std);
}